// Round 4
// baseline (8805.047 us; speedup 1.0000x reference)
//
#include <hip/hip_runtime.h>
#include <math.h>

#define B_    4096
#define A_    6
#define V_    1024
#define L_    32
#define DIN_  64
#define DOUT_ 64
#define H_    512
#define G_    2048   // 4*H
#define ROWS  16
#define NT    1024
#define AD    (A_ * DIN_)   // 384

// ---------- pack W_ih / W_hh: [4*512][K] -> [K][512] float4 (i,f,g,o) ----------
__global__ void pack_gates(const float* __restrict__ W, float4* __restrict__ Wp, int K) {
  __shared__ float tile[4][32][33];
  int k0 = blockIdx.x * 32, j0 = blockIdx.y * 32;
  int tx = threadIdx.x, ty = threadIdx.y;            // 32 x 8
  #pragma unroll
  for (int gi = 0; gi < 4; gi++)
    for (int i = ty; i < 32; i += 8)
      tile[gi][i][tx] = W[(size_t)(gi * 512 + j0 + i) * K + (k0 + tx)];
  __syncthreads();
  for (int i = ty; i < 32; i += 8) {
    float4 v = make_float4(tile[0][tx][i], tile[1][tx][i], tile[2][tx][i], tile[3][tx][i]);
    Wp[(size_t)(k0 + i) * 512 + (j0 + tx)] = v;
  }
}

// ---------- pack Wo: [512][1024] -> [128][1024] float4 (k,k+1,k+2,k+3) ----------
__global__ void pack_wo(const float* __restrict__ Wo, float4* __restrict__ Wp) {
  int v  = blockIdx.x * 256 + threadIdx.x;
  int k4 = blockIdx.y;
  Wp[(size_t)k4 * 1024 + v] = make_float4(
      Wo[(size_t)(4 * k4 + 0) * 1024 + v], Wo[(size_t)(4 * k4 + 1) * 1024 + v],
      Wo[(size_t)(4 * k4 + 2) * 1024 + v], Wo[(size_t)(4 * k4 + 3) * 1024 + v]);
}

// ---------------- fused 32-step LSTM greedy decoder ----------------
// One block owns 16 batch rows. Thread mapping (R4): gates = 2 j-cols x 4 rows,
// logits = 4 vcols x 4 rows. Halves ds_read_b128 count vs R3 (LDS return-path
// was the computed bottleneck: 34.8k DS instr/CU/step ~= 400k cyc > 213k FMA).
// waves_per_eu pinned to 4 (grid==256 -> exactly 1 block/CU) => 128 VGPR budget.
template <bool PK>
__launch_bounds__(NT)
__attribute__((amdgpu_waves_per_eu(4, 4)))
__global__ void lstm_decode(
    const int*   __restrict__ x,
    const float* __restrict__ input_emb,
    const float* __restrict__ output_emb,
    const float* __restrict__ Wi,         // [AD][H] raw
    const float* __restrict__ bi,
    const float* __restrict__ Wih,        // PK ? packed [64][512]f4 : raw [G][DOUT]
    const float* __restrict__ Whh,        // PK ? packed [512][512]f4 : raw [G][H]
    const float* __restrict__ b_ih,
    const float* __restrict__ b_hh,
    const float* __restrict__ Wo,         // PK ? packed [128][1024]f4 : raw [H][V]
    const float* __restrict__ bo,
    const float* __restrict__ sos,
    float* __restrict__ out)              // seq [B][L] then logits [B][L][V]
{
  __shared__ __align__(16) float sh[ROWS * H_];      // 32 KB
  __shared__ __align__(16) float semb[ROWS * DOUT_]; // 4 KB
  __shared__ __align__(16) float sbuf[ROWS * AD];    // 24 KB (prologue e / argmax cands)

  const int t     = threadIdx.x;
  const int r0    = blockIdx.x * ROWS;
  const int j     = t & 255;          // gate cols {j, j+256}
  const int rbase = (t >> 8) * 4;     // rows rbase..rbase+3 (wave-uniform)
  const int vcol  = t & 255;          // logit cols {vcol,+256,+512,+768}
  const int wv    = t >> 6;           // wave id 0..15

  float* out_seq    = out;
  float* out_logits = out + (size_t)B_ * L_;

  // ---- prologue: gather e = input_emb[x], init emb = sos ----
  for (int idx = t; idx < ROWS * AD; idx += NT) {
    int r   = idx / AD;
    int rem = idx - r * AD;
    int a   = rem >> 6;
    int d   = rem & 63;
    int ei  = x[(r0 + r) * A_ + a];
    sbuf[idx] = input_emb[ei * DIN_ + d];
  }
  for (int idx = t; idx < ROWS * DOUT_; idx += NT)
    semb[idx] = sos[idx & 63];
  __syncthreads();

  // ---- h0 = e @ Wi + bi  (2 cols x 4 rows per thread) ----
  {
    float acc0[4], acc1[4];
    #pragma unroll
    for (int r = 0; r < 4; r++) { acc0[r] = 0.f; acc1[r] = 0.f; }
    for (int k = 0; k < AD; k++) {
      float w0 = Wi[(size_t)k * H_ + j];
      float w1 = Wi[(size_t)k * H_ + j + 256];
      #pragma unroll
      for (int r = 0; r < 4; r++) {
        float e = sbuf[(rbase + r) * AD + k];
        acc0[r] = fmaf(e, w0, acc0[r]);
        acc1[r] = fmaf(e, w1, acc1[r]);
      }
    }
    float b0 = bi[j], b1 = bi[j + 256];
    #pragma unroll
    for (int r = 0; r < 4; r++) {
      sh[(rbase + r) * H_ + j]       = acc0[r] + b0;
      sh[(rbase + r) * H_ + j + 256] = acc1[r] + b1;
    }
  }
  __syncthreads();

  // persistent per-thread state
  float creg[2][4];
  #pragma unroll
  for (int c = 0; c < 2; c++)
    for (int r = 0; r < 4; r++) creg[c][r] = 0.f;
  float bii[2], bff[2], bgg[2], boo[2];
  #pragma unroll
  for (int c = 0; c < 2; c++) {
    int col = j + c * 256;
    bii[c] = b_ih[col]        + b_hh[col];
    bff[c] = b_ih[col + 512]  + b_hh[col + 512];
    bgg[c] = b_ih[col + 1024] + b_hh[col + 1024];
    boo[c] = b_ih[col + 1536] + b_hh[col + 1536];
  }
  float bov[4];
  #pragma unroll
  for (int cc = 0; cc < 4; cc++) bov[cc] = bo[vcol + cc * 256];

  float* cand_v = sbuf;               // [16 rows][4 wave-slots]
  int*   cand_i = (int*)(sbuf + 64);

  const float4* WpE = (const float4*)Wih;   // [64][512]  (PK)
  const float4* WpH = (const float4*)Whh;   // [512][512] (PK)
  const float4* Wop = (const float4*)Wo;    // [128][1024](PK)

  for (int step = 0; step < L_; step++) {
    // ---------- gates = bias + emb @ W_ih^T + h @ W_hh^T ----------
    float ai[2][4], af[2][4], ag[2][4], ao[2][4];
    #pragma unroll
    for (int c = 0; c < 2; c++)
      for (int r = 0; r < 4; r++) { ai[c][r] = bii[c]; af[c][r] = bff[c]; ag[c][r] = bgg[c]; ao[c][r] = boo[c]; }

    if (PK) {
      // ---- emb part (K = 64) ----
      for (int k = 0; k < DOUT_; k += 4) {
        float4 w[2][4];
        #pragma unroll
        for (int kk = 0; kk < 4; kk++) {
          w[0][kk] = WpE[(size_t)(k + kk) * 512 + j];
          w[1][kk] = WpE[(size_t)(k + kk) * 512 + j + 256];
        }
        #pragma unroll
        for (int r = 0; r < 4; r++) {
          float4 e4 = *(const float4*)&semb[(rbase + r) * DOUT_ + k];
          #pragma unroll
          for (int c = 0; c < 2; c++) {
            ai[c][r]=fmaf(e4.x,w[c][0].x,ai[c][r]); af[c][r]=fmaf(e4.x,w[c][0].y,af[c][r]); ag[c][r]=fmaf(e4.x,w[c][0].z,ag[c][r]); ao[c][r]=fmaf(e4.x,w[c][0].w,ao[c][r]);
            ai[c][r]=fmaf(e4.y,w[c][1].x,ai[c][r]); af[c][r]=fmaf(e4.y,w[c][1].y,af[c][r]); ag[c][r]=fmaf(e4.y,w[c][1].z,ag[c][r]); ao[c][r]=fmaf(e4.y,w[c][1].w,ao[c][r]);
            ai[c][r]=fmaf(e4.z,w[c][2].x,ai[c][r]); af[c][r]=fmaf(e4.z,w[c][2].y,af[c][r]); ag[c][r]=fmaf(e4.z,w[c][2].z,ag[c][r]); ao[c][r]=fmaf(e4.z,w[c][2].w,ao[c][r]);
            ai[c][r]=fmaf(e4.w,w[c][3].x,ai[c][r]); af[c][r]=fmaf(e4.w,w[c][3].y,af[c][r]); ag[c][r]=fmaf(e4.w,w[c][3].z,ag[c][r]); ao[c][r]=fmaf(e4.w,w[c][3].w,ao[c][r]);
          }
        }
      }
      // ---- h part (K = 512) ----
      for (int k = 0; k < H_; k += 4) {
        float4 w[2][4];
        #pragma unroll
        for (int kk = 0; kk < 4; kk++) {
          w[0][kk] = WpH[(size_t)(k + kk) * 512 + j];
          w[1][kk] = WpH[(size_t)(k + kk) * 512 + j + 256];
        }
        #pragma unroll
        for (int r = 0; r < 4; r++) {
          float4 h4 = *(const float4*)&sh[(rbase + r) * H_ + k];
          #pragma unroll
          for (int c = 0; c < 2; c++) {
            ai[c][r]=fmaf(h4.x,w[c][0].x,ai[c][r]); af[c][r]=fmaf(h4.x,w[c][0].y,af[c][r]); ag[c][r]=fmaf(h4.x,w[c][0].z,ag[c][r]); ao[c][r]=fmaf(h4.x,w[c][0].w,ao[c][r]);
            ai[c][r]=fmaf(h4.y,w[c][1].x,ai[c][r]); af[c][r]=fmaf(h4.y,w[c][1].y,af[c][r]); ag[c][r]=fmaf(h4.y,w[c][1].z,ag[c][r]); ao[c][r]=fmaf(h4.y,w[c][1].w,ao[c][r]);
            ai[c][r]=fmaf(h4.z,w[c][2].x,ai[c][r]); af[c][r]=fmaf(h4.z,w[c][2].y,af[c][r]); ag[c][r]=fmaf(h4.z,w[c][2].z,ag[c][r]); ao[c][r]=fmaf(h4.z,w[c][2].w,ao[c][r]);
            ai[c][r]=fmaf(h4.w,w[c][3].x,ai[c][r]); af[c][r]=fmaf(h4.w,w[c][3].y,af[c][r]); ag[c][r]=fmaf(h4.w,w[c][3].z,ag[c][r]); ao[c][r]=fmaf(h4.w,w[c][3].w,ao[c][r]);
          }
        }
      }
    } else {
      // ---- fallback: raw row-major weights ----
      for (int k = 0; k < DOUT_; k += 4) {
        float4 w[2][4];
        #pragma unroll
        for (int c = 0; c < 2; c++)
          for (int gi = 0; gi < 4; gi++)
            w[c][gi] = *(const float4*)&Wih[(size_t)(gi * 512 + j + c * 256) * DOUT_ + k];
        #pragma unroll
        for (int r = 0; r < 4; r++) {
          float4 e4 = *(const float4*)&semb[(rbase + r) * DOUT_ + k];
          #pragma unroll
          for (int c = 0; c < 2; c++) {
            ai[c][r]=fmaf(e4.x,w[c][0].x,ai[c][r]); ai[c][r]=fmaf(e4.y,w[c][0].y,ai[c][r]); ai[c][r]=fmaf(e4.z,w[c][0].z,ai[c][r]); ai[c][r]=fmaf(e4.w,w[c][0].w,ai[c][r]);
            af[c][r]=fmaf(e4.x,w[c][1].x,af[c][r]); af[c][r]=fmaf(e4.y,w[c][1].y,af[c][r]); af[c][r]=fmaf(e4.z,w[c][1].z,af[c][r]); af[c][r]=fmaf(e4.w,w[c][1].w,af[c][r]);
            ag[c][r]=fmaf(e4.x,w[c][2].x,ag[c][r]); ag[c][r]=fmaf(e4.y,w[c][2].y,ag[c][r]); ag[c][r]=fmaf(e4.z,w[c][2].z,ag[c][r]); ag[c][r]=fmaf(e4.w,w[c][2].w,ag[c][r]);
            ao[c][r]=fmaf(e4.x,w[c][3].x,ao[c][r]); ao[c][r]=fmaf(e4.y,w[c][3].y,ao[c][r]); ao[c][r]=fmaf(e4.z,w[c][3].z,ao[c][r]); ao[c][r]=fmaf(e4.w,w[c][3].w,ao[c][r]);
          }
        }
      }
      for (int k = 0; k < H_; k += 4) {
        float4 w[2][4];
        #pragma unroll
        for (int c = 0; c < 2; c++)
          for (int gi = 0; gi < 4; gi++)
            w[c][gi] = *(const float4*)&Whh[(size_t)(gi * 512 + j + c * 256) * H_ + k];
        #pragma unroll
        for (int r = 0; r < 4; r++) {
          float4 h4 = *(const float4*)&sh[(rbase + r) * H_ + k];
          #pragma unroll
          for (int c = 0; c < 2; c++) {
            ai[c][r]=fmaf(h4.x,w[c][0].x,ai[c][r]); ai[c][r]=fmaf(h4.y,w[c][0].y,ai[c][r]); ai[c][r]=fmaf(h4.z,w[c][0].z,ai[c][r]); ai[c][r]=fmaf(h4.w,w[c][0].w,ai[c][r]);
            af[c][r]=fmaf(h4.x,w[c][1].x,af[c][r]); af[c][r]=fmaf(h4.y,w[c][1].y,af[c][r]); af[c][r]=fmaf(h4.z,w[c][1].z,af[c][r]); af[c][r]=fmaf(h4.w,w[c][1].w,af[c][r]);
            ag[c][r]=fmaf(h4.x,w[c][2].x,ag[c][r]); ag[c][r]=fmaf(h4.y,w[c][2].y,ag[c][r]); ag[c][r]=fmaf(h4.z,w[c][2].z,ag[c][r]); ag[c][r]=fmaf(h4.w,w[c][2].w,ag[c][r]);
            ao[c][r]=fmaf(h4.x,w[c][3].x,ao[c][r]); ao[c][r]=fmaf(h4.y,w[c][3].y,ao[c][r]); ao[c][r]=fmaf(h4.z,w[c][3].z,ao[c][r]); ao[c][r]=fmaf(h4.w,w[c][3].w,ao[c][r]);
          }
        }
      }
    }

    // ---------- activations; c-state kept in registers ----------
    float hn[2][4];
    #pragma unroll
    for (int c = 0; c < 2; c++)
      #pragma unroll
      for (int r = 0; r < 4; r++) {
        float iv = 1.f / (1.f + expf(-ai[c][r]));
        float fv = 1.f / (1.f + expf(-af[c][r]));
        float gv = tanhf(ag[c][r]);
        float ov = 1.f / (1.f + expf(-ao[c][r]));
        float cn = fv * creg[c][r] + iv * gv;
        creg[c][r] = cn;
        hn[c][r]   = ov * tanhf(cn);
      }
    __syncthreads();                      // everyone done READING sh/semb
    #pragma unroll
    for (int r = 0; r < 4; r++) {
      sh[(rbase + r) * H_ + j]       = hn[0][r];
      sh[(rbase + r) * H_ + j + 256] = hn[1][r];
    }
    __syncthreads();                      // new h visible

    // ---------- logits: 4 vocab cols x 4 rows per thread ----------
    float lacc[4][4];                     // [cc][r]
    #pragma unroll
    for (int cc = 0; cc < 4; cc++)
      for (int r = 0; r < 4; r++) lacc[cc][r] = bov[cc];
    if (PK) {
      float4 w0 = Wop[vcol], w1 = Wop[vcol + 256], w2 = Wop[vcol + 512], w3 = Wop[vcol + 768];
      #pragma unroll 2
      for (int k4 = 0; k4 < 128; k4++) {
        const int kn = (k4 + 1 < 128) ? (k4 + 1) : 0;
        float4 n0 = Wop[(size_t)kn * 1024 + vcol];
        float4 n1 = Wop[(size_t)kn * 1024 + vcol + 256];
        float4 n2 = Wop[(size_t)kn * 1024 + vcol + 512];
        float4 n3 = Wop[(size_t)kn * 1024 + vcol + 768];
        #pragma unroll
        for (int r = 0; r < 4; r++) {
          float4 h4 = *(const float4*)&sh[(rbase + r) * H_ + (k4 << 2)];
          lacc[0][r]=fmaf(h4.x,w0.x,lacc[0][r]); lacc[0][r]=fmaf(h4.y,w0.y,lacc[0][r]); lacc[0][r]=fmaf(h4.z,w0.z,lacc[0][r]); lacc[0][r]=fmaf(h4.w,w0.w,lacc[0][r]);
          lacc[1][r]=fmaf(h4.x,w1.x,lacc[1][r]); lacc[1][r]=fmaf(h4.y,w1.y,lacc[1][r]); lacc[1][r]=fmaf(h4.z,w1.z,lacc[1][r]); lacc[1][r]=fmaf(h4.w,w1.w,lacc[1][r]);
          lacc[2][r]=fmaf(h4.x,w2.x,lacc[2][r]); lacc[2][r]=fmaf(h4.y,w2.y,lacc[2][r]); lacc[2][r]=fmaf(h4.z,w2.z,lacc[2][r]); lacc[2][r]=fmaf(h4.w,w2.w,lacc[2][r]);
          lacc[3][r]=fmaf(h4.x,w3.x,lacc[3][r]); lacc[3][r]=fmaf(h4.y,w3.y,lacc[3][r]); lacc[3][r]=fmaf(h4.z,w3.z,lacc[3][r]); lacc[3][r]=fmaf(h4.w,w3.w,lacc[3][r]);
        }
        w0 = n0; w1 = n1; w2 = n2; w3 = n3;
      }
    } else {
      for (int k = 0; k < H_; k += 4) {
        #pragma unroll
        for (int cc = 0; cc < 4; cc++) {
          int v = vcol + cc * 256;
          float a0 = Wo[(size_t)(k+0)*V_ + v], a1 = Wo[(size_t)(k+1)*V_ + v];
          float a2 = Wo[(size_t)(k+2)*V_ + v], a3 = Wo[(size_t)(k+3)*V_ + v];
          #pragma unroll
          for (int r = 0; r < 4; r++) {
            float4 h4 = *(const float4*)&sh[(rbase + r) * H_ + k];
            lacc[cc][r]=fmaf(h4.x,a0,lacc[cc][r]); lacc[cc][r]=fmaf(h4.y,a1,lacc[cc][r]);
            lacc[cc][r]=fmaf(h4.z,a2,lacc[cc][r]); lacc[cc][r]=fmaf(h4.w,a3,lacc[cc][r]);
          }
        }
      }
    }
    // nontemporal stores: logits never re-read
    #pragma unroll
    for (int r = 0; r < 4; r++) {
      float* p = &out_logits[((size_t)(r0 + rbase + r) * L_ + step) * V_ + vcol];
      __builtin_nontemporal_store(lacc[0][r], p);
      __builtin_nontemporal_store(lacc[1][r], p + 256);
      __builtin_nontemporal_store(lacc[2][r], p + 512);
      __builtin_nontemporal_store(lacc[3][r], p + 768);
    }

    // ---------- argmax (numpy: first index wins on ties) ----------
    #pragma unroll
    for (int r = 0; r < 4; r++) {
      float bv = lacc[0][r];
      int   bx = vcol;
      #pragma unroll
      for (int cc = 1; cc < 4; cc++) {
        float v = lacc[cc][r];
        if (v > bv) { bv = v; bx = vcol + cc * 256; }   // strict > keeps smaller idx
      }
      #pragma unroll
      for (int off = 32; off; off >>= 1) {
        float ov = __shfl_xor(bv, off);
        int   ox = __shfl_xor(bx, off);
        if (ov > bv || (ov == bv && ox < bx)) { bv = ov; bx = ox; }
      }
      if ((t & 63) == 0) {
        cand_v[(rbase + r) * 4 + (wv & 3)] = bv;
        cand_i[(rbase + r) * 4 + (wv & 3)] = bx;
      }
    }
    __syncthreads();

    // ---------- winner scan (redundant per emb-thread) + emb feedback ----------
    {
      int r = t >> 6;        // 0..15
      int d = t & 63;
      float bv = cand_v[r * 4];
      int   bx = cand_i[r * 4];
      #pragma unroll
      for (int c = 1; c < 4; c++) {
        float ov = cand_v[r * 4 + c];
        int   ox = cand_i[r * 4 + c];
        if (ov > bv || (ov == bv && ox < bx)) { bv = ov; bx = ox; }
      }
      if (d == 0)
        out_seq[(size_t)(r0 + r) * L_ + step] = (float)bx;
      semb[r * DOUT_ + d] = output_emb[(size_t)bx * DOUT_ + d];
    }
    __syncthreads();
  }
}

extern "C" void kernel_launch(void* const* d_in, const int* in_sizes, int n_in,
                              void* d_out, int out_size, void* d_ws, size_t ws_size,
                              hipStream_t stream) {
  const int*   x          = (const int*)  d_in[0];
  const float* input_emb  = (const float*)d_in[1];
  const float* output_emb = (const float*)d_in[2];
  const float* Wi         = (const float*)d_in[3];
  const float* bi         = (const float*)d_in[4];
  const float* W_ih       = (const float*)d_in[5];
  const float* W_hh       = (const float*)d_in[6];
  const float* b_ih       = (const float*)d_in[7];
  const float* b_hh       = (const float*)d_in[8];
  const float* Wo         = (const float*)d_in[9];
  const float* bo         = (const float*)d_in[10];
  const float* sos        = (const float*)d_in[11];
  float* out = (float*)d_out;

  const size_t n_whh = (size_t)H_ * 512;     // float4 count
  const size_t n_wih = (size_t)DOUT_ * 512;
  const size_t n_wo  = (size_t)128 * 1024;
  const size_t ws_need = (n_whh + n_wih + n_wo) * sizeof(float4);

  if (ws_size >= ws_need) {
    float4* WhhP = (float4*)d_ws;
    float4* WihP = WhhP + n_whh;
    float4* WoP  = WihP + n_wih;
    dim3 tb(32, 8);
    pack_gates<<<dim3(H_ / 32,    16), tb, 0, stream>>>(W_hh, WhhP, H_);
    pack_gates<<<dim3(DOUT_ / 32, 16), tb, 0, stream>>>(W_ih, WihP, DOUT_);
    pack_wo<<<dim3(4, 128), 256, 0, stream>>>(Wo, WoP);
    lstm_decode<true><<<B_ / ROWS, NT, 0, stream>>>(
        x, input_emb, output_emb, Wi, bi,
        (const float*)WihP, (const float*)WhhP, b_ih, b_hh,
        (const float*)WoP, bo, sos, out);
  } else {
    lstm_decode<false><<<B_ / ROWS, NT, 0, stream>>>(
        x, input_emb, output_emb, Wi, bi, W_ih, W_hh, b_ih, b_hh, Wo, bo, sos, out);
  }
}